// Round 3
// baseline (193.260 us; speedup 1.0000x reference)
//
#include <hip/hip_runtime.h>
#include <hip/hip_bf16.h>
#include <type_traits>

#define AS1 __attribute__((address_space(1)))
#define AS3 __attribute__((address_space(3)))

typedef __attribute__((ext_vector_type(4))) float f32x4;
typedef __attribute__((ext_vector_type(8))) short bf16x8;

static constexpr int B_   = 2048;
static constexpr int IN_  = 1024;
static constexpr int HID_ = 2048;
static constexpr int NB_  = 8;
static constexpr int BS_  = 256;   // block size
static constexpr int G3_  = 768;   // 3*BS_

// ---------- fp32 -> bf16 (RNE) ----------
__device__ __forceinline__ unsigned short f2bf(float f) {
  unsigned u = __builtin_bit_cast(unsigned, f);
  u = (u + 0x7FFFu + ((u >> 16) & 1u)) >> 16;
  return (unsigned short)u;
}

// One launch converts all four fp32 arrays into the contiguous bf16 region in ws.
__global__ void cvt_all(const float* __restrict__ x, const float* __restrict__ h,
                        const float* __restrict__ Wih, const float* __restrict__ Whh,
                        unsigned short* __restrict__ dst) {
  constexpr int c0 = (B_ * IN_) / 4;
  constexpr int c1 = c0 + (B_ * HID_) / 4;
  constexpr int c2 = c1 + (NB_ * G3_ * IN_) / 4;
  constexpr int n4 = c2 + (NB_ * G3_ * BS_) / 4;
  int i = blockIdx.x * blockDim.x + threadIdx.x;
  int stride = gridDim.x * blockDim.x;
  for (; i < n4; i += stride) {
    float4 v;
    if (i < c0)       v = reinterpret_cast<const float4*>(x)[i];
    else if (i < c1)  v = reinterpret_cast<const float4*>(h)[i - c0];
    else if (i < c2)  v = reinterpret_cast<const float4*>(Wih)[i - c1];
    else              v = reinterpret_cast<const float4*>(Whh)[i - c2];
    ushort4 o;
    o.x = f2bf(v.x); o.y = f2bf(v.y); o.z = f2bf(v.z); o.w = f2bf(v.w);
    reinterpret_cast<ushort4*>(dst)[i] = o;
  }
}

// ---------- fused block-GRU MFMA kernel (double-buffered, counted vmcnt) ----------
// Tile: 128 batch rows x 64 out-cols (192 gate cols); 4 waves (2x2).
// Accumulators: [0]=r (K=1280 combined), [1]=z (combined), [2]=i_n (K=1024), [3]=h_n (K=256).
// LDS: 2 buffers x { A [128][64]bf16 (16KB) + W [192][64]bf16 (24KB) }, XOR-swizzled
// (phys = logical ^ ((row&7)<<4)); global_load_lds writes linearly so the global
// SOURCE address is pre-swizzled (rule #21).
// Pipeline: stage(buf0,t0), stage(buf1,t1); loop { vmcnt(10); barrier; compute(cur);
// lgkmcnt(0); barrier; stage(cur, t+2) } — next tile's 10 loads stay in flight
// across compute (T3/T4-lite). Raw s_barrier (no compiler vmcnt(0) drain).
__global__ __launch_bounds__(256, 2) void gru_mfma(
    const unsigned short* __restrict__ inb,    // [2048][1024] bf16
    const unsigned short* __restrict__ hidb,   // [2048][2048] bf16
    const unsigned short* __restrict__ wihb,   // [8][768][1024] bf16
    const unsigned short* __restrict__ whhb,   // [8][768][256] bf16
    const float* __restrict__ hid_f32,         // [2048][2048] fp32 (h_prev)
    const float* __restrict__ b_ih,            // [8][768]
    const float* __restrict__ b_hh,            // [8][768]
    float* __restrict__ out)                   // [2048][2048]
{
  __shared__ __align__(16) char lds[2][40960];   // per buf: A at 0, W at 16384

  const int t    = threadIdx.x;
  const int lane = t & 63;
  const int wid  = t >> 6;
  const int wm   = wid >> 1;     // wave row (0..1) -> 64-row half
  const int wn   = wid & 1;      // wave col (0..1) -> 32-col half

  // Bijective XCD swizzle: nwg=512, 8 XCDs -> each XCD gets 4 column-tiles x 16 M-tiles.
  const int bid = blockIdx.x;
  const int swz = (bid & 7) * 64 + (bid >> 3);
  const int mt  = swz & 15;
  const int ct  = swz >> 4;
  const int mrow0 = mt * 128;
  const int n     = ct >> 2;          // GRU block index
  const int s0    = (ct & 3) * 64;    // col offset within block

  // Staging pass p writes phys LDS offset op = p*4096 + t*16; the element that
  // belongs there is logical ol = op ^ (((op>>7)&7)<<4) (involution on bits [6:4]).
  int arow[4], acb[4];
#pragma unroll
  for (int p = 0; p < 4; ++p) {
    int op = p * 4096 + t * 16;
    int ol = op ^ (((op >> 7) & 7) << 4);
    arow[p] = ol >> 7; acb[p] = ol & 127;
  }
  int wrowg[6], wsl[6], wcb[6];
#pragma unroll
  for (int p = 0; p < 6; ++p) {
    int op = p * 4096 + t * 16;
    int ol = op ^ (((op >> 7) & 7) << 4);
    int wr = ol >> 7;             // 0..191
    wrowg[p] = wr >> 6;           // gate 0..2
    wsl[p]   = wr & 63;           // col within 64-wide tile
    wcb[p]   = ol & 127;
  }

  f32x4 acc[4][4][2] = {};   // [set][mi][ni]

  // Issue 10 global_load_lds (4 A + 6 W) for K-tile t2 into buffer buf.
  auto stage = [&](int buf, int t2) {
    const bool ph1 = t2 < 16;
    const int ks = ph1 ? t2 : (t2 - 16);
    char* base = (char*)lds[buf];
#pragma unroll
    for (int p = 0; p < 4; ++p) {
      const char* src = ph1
        ? (const char*)inb  + ((size_t)(mrow0 + arow[p]) * IN_  + ks * 64) * 2 + acb[p]
        : (const char*)hidb + ((size_t)(mrow0 + arow[p]) * HID_ + n * BS_ + ks * 64) * 2 + acb[p];
      __builtin_amdgcn_global_load_lds((const AS1 void*)src,
                                       (AS3 void*)(base + p * 4096 + wid * 1024), 16, 0, 0);
    }
#pragma unroll
    for (int p = 0; p < 6; ++p) {
      int grow = n * G3_ + wrowg[p] * BS_ + s0 + wsl[p];
      const char* src = ph1
        ? (const char*)wihb + ((size_t)grow * IN_ + ks * 64) * 2 + wcb[p]
        : (const char*)whhb + ((size_t)grow * BS_ + ks * 64) * 2 + wcb[p];
      __builtin_amdgcn_global_load_lds((const AS1 void*)src,
                                       (AS3 void*)(base + 16384 + p * 4096 + wid * 1024), 16, 0, 0);
    }
  };

  auto compute = [&](int buf, auto ph1c) {
    constexpr bool PH1 = decltype(ph1c)::value;
    const char* Ab = (const char*)lds[buf];
    const char* Wb = (const char*)lds[buf] + 16384;
#pragma unroll
    for (int ksub = 0; ksub < 2; ++ksub) {
      bf16x8 af[4];
#pragma unroll
      for (int mi = 0; mi < 4; ++mi) {
        int ar  = wm * 64 + mi * 16 + (lane & 15);
        int off = ar * 128 + ksub * 64 + ((lane >> 4) * 16);
        off ^= (ar & 7) << 4;
        af[mi] = *reinterpret_cast<const bf16x8*>(Ab + off);
      }
#pragma unroll
      for (int g = 0; g < 3; ++g) {
        bf16x8 wf[2];
#pragma unroll
        for (int ni = 0; ni < 2; ++ni) {
          int wr  = g * 64 + wn * 32 + ni * 16 + (lane & 15);
          int off = wr * 128 + ksub * 64 + ((lane >> 4) * 16);
          off ^= (wr & 7) << 4;
          wf[ni] = *reinterpret_cast<const bf16x8*>(Wb + off);
        }
        constexpr int set2 = PH1 ? 2 : 3;
        const int set = (g < 2) ? g : set2;
#pragma unroll
        for (int mi = 0; mi < 4; ++mi)
#pragma unroll
          for (int ni = 0; ni < 2; ++ni)
            acc[set][mi][ni] = __builtin_amdgcn_mfma_f32_16x16x32_bf16(
                af[mi], wf[ni], acc[set][mi][ni], 0, 0, 0);
      }
    }
  };

  // ---- pipelined K loop: 16 input K-tiles + 4 hidden K-tiles = 20 ----
  stage(0, 0);
  stage(1, 1);
  for (int tt = 0; tt < 20; ++tt) {
    const int cur = tt & 1;
    if (tt < 19) { asm volatile("s_waitcnt vmcnt(10)" ::: "memory"); }
    else         { asm volatile("s_waitcnt vmcnt(0)"  ::: "memory"); }
    __builtin_amdgcn_sched_barrier(0);
    __builtin_amdgcn_s_barrier();          // buf[cur] fully staged for all waves
    if (tt < 16) compute(cur, std::true_type{});
    else         compute(cur, std::false_type{});
    asm volatile("s_waitcnt lgkmcnt(0)" ::: "memory");   // my ds_reads retired
    __builtin_amdgcn_sched_barrier(0);
    __builtin_amdgcn_s_barrier();          // all waves done reading buf[cur]
    if (tt + 2 < 20) stage(cur, tt + 2);   // overwrite now safe
  }

  // ---- epilogue: gates + output ----
#pragma unroll
  for (int ni = 0; ni < 2; ++ni) {
    int scol = s0 + wn * 32 + ni * 16 + (lane & 15);
    float br_i = b_ih[n * G3_ + 0 * BS_ + scol];
    float bz_i = b_ih[n * G3_ + 1 * BS_ + scol];
    float bn_i = b_ih[n * G3_ + 2 * BS_ + scol];
    float br_h = b_hh[n * G3_ + 0 * BS_ + scol];
    float bz_h = b_hh[n * G3_ + 1 * BS_ + scol];
    float bn_h = b_hh[n * G3_ + 2 * BS_ + scol];
    int gcol = n * BS_ + scol;
#pragma unroll
    for (int mi = 0; mi < 4; ++mi) {
#pragma unroll
      for (int i = 0; i < 4; ++i) {
        int row = mrow0 + wm * 64 + mi * 16 + (lane >> 4) * 4 + i;  // C/D: col=lane&15, row=(lane>>4)*4+reg
        float hprev = hid_f32[(size_t)row * HID_ + gcol];
        float rr = acc[0][mi][ni][i] + br_i + br_h;
        float zz = acc[1][mi][ni][i] + bz_i + bz_h;
        float r  = 1.f / (1.f + __expf(-rr));
        float z  = 1.f / (1.f + __expf(-zz));
        float ng = tanhf(acc[2][mi][ni][i] + bn_i + r * (acc[3][mi][ni][i] + bn_h));
        out[(size_t)row * HID_ + gcol] = (1.f - z) * ng + z * hprev;
      }
    }
  }
}

// ---------- fallback (only if ws too small): naive fp32 ----------
__global__ void gru_naive(const float* __restrict__ x, const float* __restrict__ h,
                          const float* __restrict__ Wih, const float* __restrict__ Whh,
                          const float* __restrict__ bih, const float* __restrict__ bhh,
                          float* __restrict__ out) {
  int b = blockIdx.x;
  int n = blockIdx.y;
  int s = threadIdx.x;   // 256
  __shared__ float xs[1024];
  __shared__ float hs[256];
  for (int i = threadIdx.x; i < 1024; i += 256) xs[i] = x[(size_t)b * IN_ + i];
  if (threadIdx.x < 256) hs[threadIdx.x] = h[(size_t)b * HID_ + n * BS_ + threadIdx.x];
  __syncthreads();
  float gi[3], gh[3];
  for (int g = 0; g < 3; ++g) {
    const float* w = Wih + ((size_t)(n * G3_ + g * BS_ + s)) * IN_;
    float a = 0.f;
    for (int k = 0; k < IN_; ++k) a += xs[k] * w[k];
    gi[g] = a + bih[n * G3_ + g * BS_ + s];
    const float* w2 = Whh + ((size_t)(n * G3_ + g * BS_ + s)) * BS_;
    float a2 = 0.f;
    for (int k = 0; k < BS_; ++k) a2 += hs[k] * w2[k];
    gh[g] = a2 + bhh[n * G3_ + g * BS_ + s];
  }
  float r = 1.f / (1.f + expf(-(gi[0] + gh[0])));
  float z = 1.f / (1.f + expf(-(gi[1] + gh[1])));
  float ng = tanhf(gi[2] + r * gh[2]);
  out[(size_t)b * HID_ + n * BS_ + s] = (1.f - z) * ng + z * hs[s];
}

extern "C" void kernel_launch(void* const* d_in, const int* in_sizes, int n_in,
                              void* d_out, int out_size, void* d_ws, size_t ws_size,
                              hipStream_t stream) {
  const float* x   = (const float*)d_in[0];
  const float* h   = (const float*)d_in[1];
  const float* Wih = (const float*)d_in[2];
  const float* Whh = (const float*)d_in[3];
  const float* bih = (const float*)d_in[4];
  const float* bhh = (const float*)d_in[5];
  float* out = (float*)d_out;

  const size_t szin  = (size_t)B_ * IN_;
  const size_t szhid = (size_t)B_ * HID_;
  const size_t szwih = (size_t)NB_ * G3_ * IN_;
  const size_t szwhh = (size_t)NB_ * G3_ * BS_;
  const size_t need  = (szin + szhid + szwih + szwhh) * 2;

  if (ws_size >= need) {
    unsigned short* inb  = (unsigned short*)d_ws;
    unsigned short* hidb = inb + szin;
    unsigned short* wihb = hidb + szhid;
    unsigned short* whhb = wihb + szwih;
    cvt_all<<<2048, 256, 0, stream>>>(x, h, Wih, Whh, (unsigned short*)d_ws);
    gru_mfma<<<512, 256, 0, stream>>>(inb, hidb, wihb, whhb, h, bih, bhh, out);
  } else {
    dim3 grid(B_, NB_);
    gru_naive<<<grid, 256, 0, stream>>>(x, h, Wih, Whh, bih, bhh, out);
  }
}

// Round 4
// 57.273 us; speedup vs baseline: 3.3744x; 3.3744x over previous
//
#include <hip/hip_runtime.h>
#include <hip/hip_bf16.h>
#include <type_traits>

#define AS1 __attribute__((address_space(1)))
#define AS3 __attribute__((address_space(3)))

typedef __attribute__((ext_vector_type(4))) float f32x4;
typedef __attribute__((ext_vector_type(8))) short bf16x8;

static constexpr int B_   = 2048;
static constexpr int IN_  = 1024;
static constexpr int HID_ = 2048;
static constexpr int NB_  = 8;
static constexpr int BS_  = 256;   // block size
static constexpr int G3_  = 768;   // 3*BS_

// ---------- fp32 -> bf16 (RNE) ----------
__device__ __forceinline__ unsigned short f2bf(float f) {
  unsigned u = __builtin_bit_cast(unsigned, f);
  u = (u + 0x7FFFu + ((u >> 16) & 1u)) >> 16;
  return (unsigned short)u;
}

// One launch converts all four fp32 arrays into the contiguous bf16 region in ws.
__global__ void cvt_all(const float* __restrict__ x, const float* __restrict__ h,
                        const float* __restrict__ Wih, const float* __restrict__ Whh,
                        unsigned short* __restrict__ dst) {
  constexpr int c0 = (B_ * IN_) / 4;
  constexpr int c1 = c0 + (B_ * HID_) / 4;
  constexpr int c2 = c1 + (NB_ * G3_ * IN_) / 4;
  constexpr int n4 = c2 + (NB_ * G3_ * BS_) / 4;
  int i = blockIdx.x * blockDim.x + threadIdx.x;
  int stride = gridDim.x * blockDim.x;
  for (; i < n4; i += stride) {
    float4 v;
    if (i < c0)       v = reinterpret_cast<const float4*>(x)[i];
    else if (i < c1)  v = reinterpret_cast<const float4*>(h)[i - c0];
    else if (i < c2)  v = reinterpret_cast<const float4*>(Wih)[i - c1];
    else              v = reinterpret_cast<const float4*>(Whh)[i - c2];
    ushort4 o;
    o.x = f2bf(v.x); o.y = f2bf(v.y); o.z = f2bf(v.z); o.w = f2bf(v.w);
    reinterpret_cast<ushort4*>(dst)[i] = o;
  }
}

// ---------- fused block-GRU MFMA kernel (static double-buffer pipeline) ----------
// Tile: 128 batch rows x 64 out-cols (192 gate cols); 4 waves (2x2).
// Accumulators: [0]=r (K=1280 combined), [1]=z (combined), [2]=i_n (K=1024), [3]=h_n (K=256).
// LDS: 2 buffers x { A [128][64]bf16 (16KB) + W [192][64]bf16 (24KB) }, XOR-swizzled
// (phys = logical ^ ((row&7)<<4)); global_load_lds writes linearly so the global
// SOURCE address is pre-swizzled (rule #21).
// Pipeline (FULLY UNROLLED, all phases static; clobber-free waitcnt + sched_barrier
// per m201 template): stage(0,t0), stage(1,t1); per step: vmcnt(10) [keeps next
// tile's 10 loads in flight]; s_barrier; compute; lgkmcnt(0); s_barrier; stage(t+2).
__global__ __launch_bounds__(256, 2) void gru_mfma(
    const unsigned short* __restrict__ inb,    // [2048][1024] bf16
    const unsigned short* __restrict__ hidb,   // [2048][2048] bf16
    const unsigned short* __restrict__ wihb,   // [8][768][1024] bf16
    const unsigned short* __restrict__ whhb,   // [8][768][256] bf16
    const float* __restrict__ hid_f32,         // [2048][2048] fp32 (h_prev)
    const float* __restrict__ b_ih,            // [8][768]
    const float* __restrict__ b_hh,            // [8][768]
    float* __restrict__ out)                   // [2048][2048]
{
  __shared__ __align__(16) char lds[2][40960];   // per buf: A at 0, W at 16384

  const int t    = threadIdx.x;
  const int lane = t & 63;
  const int wid  = t >> 6;
  const int wm   = wid >> 1;     // wave row (0..1) -> 64-row half
  const int wn   = wid & 1;      // wave col (0..1) -> 32-col half

  // Bijective XCD swizzle: nwg=512 = 8 XCDs x 64. XCD x gets swz in [x*64, x*64+64)
  // -> ct = swz>>4 in [x*4, x*4+4) -> each XCD owns exactly one GRU block n
  // (W/hid panels L2-resident) and all 16 M-tiles.
  const int bid = blockIdx.x;
  const int swz = (bid & 7) * 64 + (bid >> 3);
  const int mt  = swz & 15;
  const int ct  = swz >> 4;
  const int mrow0 = mt * 128;
  const int n     = ct >> 2;          // GRU block index
  const int s0    = (ct & 3) * 64;    // col offset within block

  // Staging pass p writes phys LDS offset op = p*4096 + t*16; the element that
  // belongs there is logical ol = op ^ (((op>>7)&7)<<4) (involution on bits [6:4]).
  int arow[4], acb[4];
#pragma unroll
  for (int p = 0; p < 4; ++p) {
    int op = p * 4096 + t * 16;
    int ol = op ^ (((op >> 7) & 7) << 4);
    arow[p] = ol >> 7; acb[p] = ol & 127;
  }
  int wrowg[6], wsl[6], wcb[6];
#pragma unroll
  for (int p = 0; p < 6; ++p) {
    int op = p * 4096 + t * 16;
    int ol = op ^ (((op >> 7) & 7) << 4);
    int wr = ol >> 7;             // 0..191
    wrowg[p] = wr >> 6;           // gate 0..2
    wsl[p]   = wr & 63;           // col within 64-wide tile
    wcb[p]   = ol & 127;
  }

  f32x4 acc[4][4][2] = {};   // [set][mi][ni]

  // Issue 10 global_load_lds (4 A + 6 W) for K-tile t2 into buffer buf.
  // Called only with compile-time buf/t2 (inside the unrolled loop).
  auto stage = [&](int buf, int t2) {
    const bool ph1 = t2 < 16;
    const int ks = ph1 ? t2 : (t2 - 16);
    char* base = (char*)lds[buf];
#pragma unroll
    for (int p = 0; p < 4; ++p) {
      const char* src = ph1
        ? (const char*)inb  + ((size_t)(mrow0 + arow[p]) * IN_  + ks * 64) * 2 + acb[p]
        : (const char*)hidb + ((size_t)(mrow0 + arow[p]) * HID_ + n * BS_ + ks * 64) * 2 + acb[p];
      __builtin_amdgcn_global_load_lds((const AS1 void*)src,
                                       (AS3 void*)(base + p * 4096 + wid * 1024), 16, 0, 0);
    }
#pragma unroll
    for (int p = 0; p < 6; ++p) {
      int grow = n * G3_ + wrowg[p] * BS_ + s0 + wsl[p];
      const char* src = ph1
        ? (const char*)wihb + ((size_t)grow * IN_ + ks * 64) * 2 + wcb[p]
        : (const char*)whhb + ((size_t)grow * BS_ + ks * 64) * 2 + wcb[p];
      __builtin_amdgcn_global_load_lds((const AS1 void*)src,
                                       (AS3 void*)(base + 16384 + p * 4096 + wid * 1024), 16, 0, 0);
    }
  };

  auto compute = [&](int buf, auto ph1c) {
    constexpr bool PH1 = decltype(ph1c)::value;
    const char* Ab = (const char*)lds[buf];
    const char* Wb = (const char*)lds[buf] + 16384;
#pragma unroll
    for (int ksub = 0; ksub < 2; ++ksub) {
      bf16x8 af[4];
#pragma unroll
      for (int mi = 0; mi < 4; ++mi) {
        int ar  = wm * 64 + mi * 16 + (lane & 15);
        int off = ar * 128 + ksub * 64 + ((lane >> 4) * 16);
        off ^= (ar & 7) << 4;
        af[mi] = *reinterpret_cast<const bf16x8*>(Ab + off);
      }
#pragma unroll
      for (int g = 0; g < 3; ++g) {
        bf16x8 wf[2];
#pragma unroll
        for (int ni = 0; ni < 2; ++ni) {
          int wr  = g * 64 + wn * 32 + ni * 16 + (lane & 15);
          int off = wr * 128 + ksub * 64 + ((lane >> 4) * 16);
          off ^= (wr & 7) << 4;
          wf[ni] = *reinterpret_cast<const bf16x8*>(Wb + off);
        }
        constexpr int set2 = PH1 ? 2 : 3;
        const int set = (g < 2) ? g : set2;
#pragma unroll
        for (int mi = 0; mi < 4; ++mi)
#pragma unroll
          for (int ni = 0; ni < 2; ++ni)
            acc[set][mi][ni] = __builtin_amdgcn_mfma_f32_16x16x32_bf16(
                af[mi], wf[ni], acc[set][mi][ni], 0, 0, 0);
      }
    }
  };

  // ---- fully-unrolled pipelined K loop: 16 input K-tiles + 4 hidden = 20 ----
  stage(0, 0);
  stage(1, 1);
#pragma unroll
  for (int tt = 0; tt < 20; ++tt) {
    const int cur = tt & 1;   // compile-time under full unroll
    __builtin_amdgcn_sched_barrier(0);
    if (tt < 19) asm volatile("s_waitcnt vmcnt(10)");
    else         asm volatile("s_waitcnt vmcnt(0)");
    __builtin_amdgcn_sched_barrier(0);
    __builtin_amdgcn_s_barrier();          // buf[cur] fully staged for all waves
    if (tt < 16) compute(cur, std::true_type{});
    else         compute(cur, std::false_type{});
    asm volatile("s_waitcnt lgkmcnt(0)");  // my ds_reads from buf[cur] retired
    __builtin_amdgcn_sched_barrier(0);
    __builtin_amdgcn_s_barrier();          // all waves done reading buf[cur]
    if (tt + 2 < 20) stage(cur, tt + 2);   // overwrite now safe
  }

  // ---- epilogue: gates + output ----
#pragma unroll
  for (int ni = 0; ni < 2; ++ni) {
    int scol = s0 + wn * 32 + ni * 16 + (lane & 15);
    float br_i = b_ih[n * G3_ + 0 * BS_ + scol];
    float bz_i = b_ih[n * G3_ + 1 * BS_ + scol];
    float bn_i = b_ih[n * G3_ + 2 * BS_ + scol];
    float br_h = b_hh[n * G3_ + 0 * BS_ + scol];
    float bz_h = b_hh[n * G3_ + 1 * BS_ + scol];
    float bn_h = b_hh[n * G3_ + 2 * BS_ + scol];
    int gcol = n * BS_ + scol;
#pragma unroll
    for (int mi = 0; mi < 4; ++mi) {
#pragma unroll
      for (int i = 0; i < 4; ++i) {
        int row = mrow0 + wm * 64 + mi * 16 + (lane >> 4) * 4 + i;  // C/D: col=lane&15, row=(lane>>4)*4+reg
        float hprev = hid_f32[(size_t)row * HID_ + gcol];
        float rr = acc[0][mi][ni][i] + br_i + br_h;
        float zz = acc[1][mi][ni][i] + bz_i + bz_h;
        float r  = 1.f / (1.f + __expf(-rr));
        float z  = 1.f / (1.f + __expf(-zz));
        float ng = tanhf(acc[2][mi][ni][i] + bn_i + r * (acc[3][mi][ni][i] + bn_h));
        out[(size_t)row * HID_ + gcol] = (1.f - z) * ng + z * hprev;
      }
    }
  }
}

// ---------- fallback (only if ws too small): naive fp32 ----------
__global__ void gru_naive(const float* __restrict__ x, const float* __restrict__ h,
                          const float* __restrict__ Wih, const float* __restrict__ Whh,
                          const float* __restrict__ bih, const float* __restrict__ bhh,
                          float* __restrict__ out) {
  int b = blockIdx.x;
  int n = blockIdx.y;
  int s = threadIdx.x;   // 256
  __shared__ float xs[1024];
  __shared__ float hs[256];
  for (int i = threadIdx.x; i < 1024; i += 256) xs[i] = x[(size_t)b * IN_ + i];
  if (threadIdx.x < 256) hs[threadIdx.x] = h[(size_t)b * HID_ + n * BS_ + threadIdx.x];
  __syncthreads();
  float gi[3], gh[3];
  for (int g = 0; g < 3; ++g) {
    const float* w = Wih + ((size_t)(n * G3_ + g * BS_ + s)) * IN_;
    float a = 0.f;
    for (int k = 0; k < IN_; ++k) a += xs[k] * w[k];
    gi[g] = a + bih[n * G3_ + g * BS_ + s];
    const float* w2 = Whh + ((size_t)(n * G3_ + g * BS_ + s)) * BS_;
    float a2 = 0.f;
    for (int k = 0; k < BS_; ++k) a2 += hs[k] * w2[k];
    gh[g] = a2 + bhh[n * G3_ + g * BS_ + s];
  }
  float r = 1.f / (1.f + expf(-(gi[0] + gh[0])));
  float z = 1.f / (1.f + expf(-(gi[1] + gh[1])));
  float ng = tanhf(gi[2] + r * gh[2]);
  out[(size_t)b * HID_ + n * BS_ + s] = (1.f - z) * ng + z * hs[s];
}

extern "C" void kernel_launch(void* const* d_in, const int* in_sizes, int n_in,
                              void* d_out, int out_size, void* d_ws, size_t ws_size,
                              hipStream_t stream) {
  const float* x   = (const float*)d_in[0];
  const float* h   = (const float*)d_in[1];
  const float* Wih = (const float*)d_in[2];
  const float* Whh = (const float*)d_in[3];
  const float* bih = (const float*)d_in[4];
  const float* bhh = (const float*)d_in[5];
  float* out = (float*)d_out;

  const size_t szin  = (size_t)B_ * IN_;
  const size_t szhid = (size_t)B_ * HID_;
  const size_t szwih = (size_t)NB_ * G3_ * IN_;
  const size_t szwhh = (size_t)NB_ * G3_ * BS_;
  const size_t need  = (szin + szhid + szwih + szwhh) * 2;

  if (ws_size >= need) {
    unsigned short* inb  = (unsigned short*)d_ws;
    unsigned short* hidb = inb + szin;
    unsigned short* wihb = hidb + szhid;
    unsigned short* whhb = wihb + szwih;
    cvt_all<<<2048, 256, 0, stream>>>(x, h, Wih, Whh, (unsigned short*)d_ws);
    gru_mfma<<<512, 256, 0, stream>>>(inb, hidb, wihb, whhb, h, bih, bhh, out);
  } else {
    dim3 grid(B_, NB_);
    gru_naive<<<grid, 256, 0, stream>>>(x, h, Wih, Whh, bih, bhh, out);
  }
}

// Round 5
// 56.888 us; speedup vs baseline: 3.3972x; 1.0068x over previous
//
#include <hip/hip_runtime.h>
#include <hip/hip_bf16.h>
#include <type_traits>

#define AS1 __attribute__((address_space(1)))
#define AS3 __attribute__((address_space(3)))

typedef __attribute__((ext_vector_type(4))) float f32x4;
typedef __attribute__((ext_vector_type(8))) short bf16x8;

template <int V> using ic = std::integral_constant<int, V>;

static constexpr int B_   = 2048;
static constexpr int IN_  = 1024;
static constexpr int HID_ = 2048;
static constexpr int NB_  = 8;
static constexpr int BS_  = 256;   // block size
static constexpr int G3_  = 768;   // 3*BS_

// ---------- fp32 -> bf16 (RNE) ----------
__device__ __forceinline__ unsigned short f2bf(float f) {
  unsigned u = __builtin_bit_cast(unsigned, f);
  u = (u + 0x7FFFu + ((u >> 16) & 1u)) >> 16;
  return (unsigned short)u;
}

// One launch converts all four fp32 arrays into the contiguous bf16 region in ws.
__global__ void cvt_all(const float* __restrict__ x, const float* __restrict__ h,
                        const float* __restrict__ Wih, const float* __restrict__ Whh,
                        unsigned short* __restrict__ dst) {
  constexpr int c0 = (B_ * IN_) / 4;
  constexpr int c1 = c0 + (B_ * HID_) / 4;
  constexpr int c2 = c1 + (NB_ * G3_ * IN_) / 4;
  constexpr int n4 = c2 + (NB_ * G3_ * BS_) / 4;
  int i = blockIdx.x * blockDim.x + threadIdx.x;
  int stride = gridDim.x * blockDim.x;
  for (; i < n4; i += stride) {
    float4 v;
    if (i < c0)       v = reinterpret_cast<const float4*>(x)[i];
    else if (i < c1)  v = reinterpret_cast<const float4*>(h)[i - c0];
    else if (i < c2)  v = reinterpret_cast<const float4*>(Wih)[i - c1];
    else              v = reinterpret_cast<const float4*>(Whh)[i - c2];
    ushort4 o;
    o.x = f2bf(v.x); o.y = f2bf(v.y); o.z = f2bf(v.z); o.w = f2bf(v.w);
    reinterpret_cast<ushort4*>(dst)[i] = o;
  }
}

// ---------- fused block-GRU MFMA kernel (3-phase-per-K-step pipeline) ----------
// Tile: 128 batch rows x 64 out-cols (192 gate cols); 4 waves (2x2).
// Accumulators: [0]=r (K=1280 combined), [1]=z (combined), [2]=i_n, [3]=h_n.
// LDS per buffer (40KB): A [128][64]bf16 @0, W [192][64]bf16 @16384 (Wg = gate g
// at 16384+g*8192). XOR-swizzle phys = logical ^ ((row&7)<<4); global_load_lds
// writes linearly so the global SOURCE address is pre-swizzled (rule #21).
//
// Per K-step T (cur = buf[T&1]), phases (m201 template: ds_read; stage-issue;
// barrier; lgkmcnt(0); setprio; MFMA; setprio; barrier):
//  P0: read A(8)+Wg0(4) frags; issue Wg2[T+1] (region freed at T-1's P2); g0 MFMAs
//  P1: read Wg1(4); issue A+Wg0[T+2] into cur (A freed by P0 - A lives in regs); g1
//  P2: read Wg2(4); issue Wg1[T+2]; vmcnt(8) [validates tile T+1, never 0]; g2
// Unified stage pass index: 0-3 = A, 4-5 = Wg0, 6-7 = Wg1, 8-9 = Wg2.
__global__ __launch_bounds__(256, 2) void gru_mfma(
    const unsigned short* __restrict__ inb,    // [2048][1024] bf16
    const unsigned short* __restrict__ hidb,   // [2048][2048] bf16
    const unsigned short* __restrict__ wihb,   // [8][768][1024] bf16
    const unsigned short* __restrict__ whhb,   // [8][768][256] bf16
    const float* __restrict__ hid_f32,         // [2048][2048] fp32 (h_prev)
    const float* __restrict__ b_ih,            // [8][768]
    const float* __restrict__ b_hh,            // [8][768]
    float* __restrict__ out)                   // [2048][2048]
{
  __shared__ __align__(16) char lds[2][40960];

  const int t    = threadIdx.x;
  const int lane = t & 63;
  const int wid  = t >> 6;
  const int wm   = wid >> 1;     // wave row (0..1) -> 64-row half
  const int wn   = wid & 1;      // wave col (0..1) -> 32-col half

  // Bijective XCD swizzle: nwg=512 = 8 XCDs x 64 -> each XCD owns one GRU block n.
  const int bid = blockIdx.x;
  const int swz = (bid & 7) * 64 + (bid >> 3);
  const int mt  = swz & 15;
  const int ct  = swz >> 4;
  const int mrow0 = mt * 128;
  const int n     = ct >> 2;          // GRU block index
  const int s0    = (ct & 3) * 64;    // col offset within block

  // Staging pass p writes phys LDS offset op = p*4096 + t*16 within its region;
  // logical ol = op ^ (((op>>7)&7)<<4) (involution on byte bits [6:4]).
  int arow[4], acb[4];
#pragma unroll
  for (int p = 0; p < 4; ++p) {
    int op = p * 4096 + t * 16;
    int ol = op ^ (((op >> 7) & 7) << 4);
    arow[p] = ol >> 7; acb[p] = ol & 127;
  }
  int wrowg[6], wsl[6], wcb[6];
#pragma unroll
  for (int p = 0; p < 6; ++p) {
    int op = p * 4096 + t * 16;
    int ol = op ^ (((op >> 7) & 7) << 4);
    int wr = ol >> 7;             // 0..191
    wrowg[p] = wr >> 6;           // gate 0..2
    wsl[p]   = wr & 63;           // col within 64-wide tile
    wcb[p]   = ol & 127;
  }

  f32x4 acc[4][4][2] = {};   // [set][mi][ni]

  // Issue stage passes [from,to) for K-tile t2 into buffer buf.
  // Pass 0-3: A; pass 4-9: W (q = p-4, gate = q>>1).
  auto stage = [&](int buf, int t2, int from, int to) {
    const bool ph1 = t2 < 16;
    const int ks = ph1 ? t2 : (t2 - 16);
    char* base = (char*)lds[buf];
#pragma unroll
    for (int p = 0; p < 10; ++p) {
      if (p < from || p >= to) continue;    // folds: from/to constant after inline
      if (p < 4) {
        const char* src = ph1
          ? (const char*)inb  + ((size_t)(mrow0 + arow[p]) * IN_  + ks * 64) * 2 + acb[p]
          : (const char*)hidb + ((size_t)(mrow0 + arow[p]) * HID_ + n * BS_ + ks * 64) * 2 + acb[p];
        __builtin_amdgcn_global_load_lds((const AS1 void*)src,
                                         (AS3 void*)(base + p * 4096 + wid * 1024), 16, 0, 0);
      } else {
        const int q = p - 4;
        int grow = n * G3_ + wrowg[q] * BS_ + s0 + wsl[q];
        const char* src = ph1
          ? (const char*)wihb + ((size_t)grow * IN_ + ks * 64) * 2 + wcb[q]
          : (const char*)whhb + ((size_t)grow * BS_ + ks * 64) * 2 + wcb[q];
        __builtin_amdgcn_global_load_lds((const AS1 void*)src,
                                         (AS3 void*)(base + 16384 + q * 4096 + wid * 1024), 16, 0, 0);
      }
    }
  };

  auto loadA = [&](int buf, bf16x8 (&af)[2][4]) {
#pragma unroll
    for (int ksub = 0; ksub < 2; ++ksub)
#pragma unroll
      for (int mi = 0; mi < 4; ++mi) {
        int ar  = wm * 64 + mi * 16 + (lane & 15);
        int off = ar * 128 + ksub * 64 + ((lane >> 4) * 16);
        off ^= (ar & 7) << 4;
        af[ksub][mi] = *reinterpret_cast<const bf16x8*>((const char*)lds[buf] + off);
      }
  };
  auto loadW = [&](int buf, int g, bf16x8 (&wf)[2][2]) {
#pragma unroll
    for (int ksub = 0; ksub < 2; ++ksub)
#pragma unroll
      for (int ni = 0; ni < 2; ++ni) {
        int wr  = g * 64 + wn * 32 + ni * 16 + (lane & 15);
        int off = wr * 128 + ksub * 64 + ((lane >> 4) * 16);
        off ^= (wr & 7) << 4;
        wf[ksub][ni] = *reinterpret_cast<const bf16x8*>((const char*)lds[buf] + 16384 + off);
      }
  };
  auto mfmaSet = [&](auto setc, bf16x8 (&af)[2][4], bf16x8 (&wf)[2][2]) {
    constexpr int set = decltype(setc)::value;
    __builtin_amdgcn_s_setprio(1);
#pragma unroll
    for (int ksub = 0; ksub < 2; ++ksub)
#pragma unroll
      for (int mi = 0; mi < 4; ++mi)
#pragma unroll
        for (int ni = 0; ni < 2; ++ni)
          acc[set][mi][ni] = __builtin_amdgcn_mfma_f32_16x16x32_bf16(
              af[ksub][mi], wf[ksub][ni], acc[set][mi][ni], 0, 0, 0);
    __builtin_amdgcn_s_setprio(0);
  };

  // ---- prologue: tile0 fully, tile1 A+Wg0+Wg1 (its Wg2 issues at step0 P0) ----
  stage(0, 0, 0, 10);
  stage(1, 1, 0, 8);
  __builtin_amdgcn_sched_barrier(0);
  asm volatile("s_waitcnt vmcnt(8)");     // tile0 landed; tile1's 8 in flight
  __builtin_amdgcn_sched_barrier(0);
  __builtin_amdgcn_s_barrier();

  // ---- 20 K-steps (16 input + 4 hidden), fully unrolled ----
#pragma unroll
  for (int tt = 0; tt < 20; ++tt) {
    const int cur = tt & 1, oth = cur ^ 1;
    bf16x8 af[2][4], wf[2][2];

    // P0: gate 0
    loadA(cur, af);
    loadW(cur, 0, wf);
    if (tt + 1 < 20) stage(oth, tt + 1, 8, 10);     // Wg2 of tile t+1
    __builtin_amdgcn_s_barrier();
    asm volatile("s_waitcnt lgkmcnt(0)");
    __builtin_amdgcn_sched_barrier(0);
    mfmaSet(ic<0>{}, af, wf);
    __builtin_amdgcn_s_barrier();

    // P1: gate 1 (A region of cur now free -> restage; A lives in regs)
    loadW(cur, 1, wf);
    if (tt + 2 < 20) stage(cur, tt + 2, 0, 6);      // A + Wg0 of tile t+2
    __builtin_amdgcn_s_barrier();
    asm volatile("s_waitcnt lgkmcnt(0)");
    __builtin_amdgcn_sched_barrier(0);
    mfmaSet(ic<1>{}, af, wf);
    __builtin_amdgcn_s_barrier();

    // P2: gate 2 (Wg1 of cur now free)
    loadW(cur, 2, wf);
    if (tt + 2 < 20) stage(cur, tt + 2, 6, 8);      // Wg1 of tile t+2
    __builtin_amdgcn_sched_barrier(0);
    if (tt <= 17)      asm volatile("s_waitcnt vmcnt(8)");  // tile t+1 valid
    else if (tt == 18) asm volatile("s_waitcnt vmcnt(0)");
    __builtin_amdgcn_sched_barrier(0);
    __builtin_amdgcn_s_barrier();
    asm volatile("s_waitcnt lgkmcnt(0)");
    __builtin_amdgcn_sched_barrier(0);
    if (tt < 16) mfmaSet(ic<2>{}, af, wf);
    else         mfmaSet(ic<3>{}, af, wf);
    __builtin_amdgcn_s_barrier();
  }

  // ---- epilogue: gates + output ----
#pragma unroll
  for (int ni = 0; ni < 2; ++ni) {
    int scol = s0 + wn * 32 + ni * 16 + (lane & 15);
    float br_i = b_ih[n * G3_ + 0 * BS_ + scol];
    float bz_i = b_ih[n * G3_ + 1 * BS_ + scol];
    float bn_i = b_ih[n * G3_ + 2 * BS_ + scol];
    float br_h = b_hh[n * G3_ + 0 * BS_ + scol];
    float bz_h = b_hh[n * G3_ + 1 * BS_ + scol];
    float bn_h = b_hh[n * G3_ + 2 * BS_ + scol];
    int gcol = n * BS_ + scol;
#pragma unroll
    for (int mi = 0; mi < 4; ++mi) {
#pragma unroll
      for (int i = 0; i < 4; ++i) {
        int row = mrow0 + wm * 64 + mi * 16 + (lane >> 4) * 4 + i;  // C/D: col=lane&15, row=(lane>>4)*4+reg
        float hprev = hid_f32[(size_t)row * HID_ + gcol];
        float rr = acc[0][mi][ni][i] + br_i + br_h;
        float zz = acc[1][mi][ni][i] + bz_i + bz_h;
        float r  = 1.f / (1.f + __expf(-rr));
        float z  = 1.f / (1.f + __expf(-zz));
        float ng = tanhf(acc[2][mi][ni][i] + bn_i + r * (acc[3][mi][ni][i] + bn_h));
        out[(size_t)row * HID_ + gcol] = (1.f - z) * ng + z * hprev;
      }
    }
  }
}

// ---------- fallback (only if ws too small): naive fp32 ----------
__global__ void gru_naive(const float* __restrict__ x, const float* __restrict__ h,
                          const float* __restrict__ Wih, const float* __restrict__ Whh,
                          const float* __restrict__ bih, const float* __restrict__ bhh,
                          float* __restrict__ out) {
  int b = blockIdx.x;
  int n = blockIdx.y;
  int s = threadIdx.x;   // 256
  __shared__ float xs[1024];
  __shared__ float hs[256];
  for (int i = threadIdx.x; i < 1024; i += 256) xs[i] = x[(size_t)b * IN_ + i];
  if (threadIdx.x < 256) hs[threadIdx.x] = h[(size_t)b * HID_ + n * BS_ + threadIdx.x];
  __syncthreads();
  float gi[3], gh[3];
  for (int g = 0; g < 3; ++g) {
    const float* w = Wih + ((size_t)(n * G3_ + g * BS_ + s)) * IN_;
    float a = 0.f;
    for (int k = 0; k < IN_; ++k) a += xs[k] * w[k];
    gi[g] = a + bih[n * G3_ + g * BS_ + s];
    const float* w2 = Whh + ((size_t)(n * G3_ + g * BS_ + s)) * BS_;
    float a2 = 0.f;
    for (int k = 0; k < BS_; ++k) a2 += hs[k] * w2[k];
    gh[g] = a2 + bhh[n * G3_ + g * BS_ + s];
  }
  float r = 1.f / (1.f + expf(-(gi[0] + gh[0])));
  float z = 1.f / (1.f + expf(-(gi[1] + gh[1])));
  float ng = tanhf(gi[2] + r * gh[2]);
  out[(size_t)b * HID_ + n * BS_ + s] = (1.f - z) * ng + z * hs[s];
}

extern "C" void kernel_launch(void* const* d_in, const int* in_sizes, int n_in,
                              void* d_out, int out_size, void* d_ws, size_t ws_size,
                              hipStream_t stream) {
  const float* x   = (const float*)d_in[0];
  const float* h   = (const float*)d_in[1];
  const float* Wih = (const float*)d_in[2];
  const float* Whh = (const float*)d_in[3];
  const float* bih = (const float*)d_in[4];
  const float* bhh = (const float*)d_in[5];
  float* out = (float*)d_out;

  const size_t szin  = (size_t)B_ * IN_;
  const size_t szhid = (size_t)B_ * HID_;
  const size_t szwih = (size_t)NB_ * G3_ * IN_;
  const size_t szwhh = (size_t)NB_ * G3_ * BS_;
  const size_t need  = (szin + szhid + szwih + szwhh) * 2;

  if (ws_size >= need) {
    unsigned short* inb  = (unsigned short*)d_ws;
    unsigned short* hidb = inb + szin;
    unsigned short* wihb = hidb + szhid;
    unsigned short* whhb = wihb + szwih;
    cvt_all<<<2048, 256, 0, stream>>>(x, h, Wih, Whh, (unsigned short*)d_ws);
    gru_mfma<<<512, 256, 0, stream>>>(inb, hidb, wihb, whhb, h, bih, bhh, out);
  } else {
    dim3 grid(B_, NB_);
    gru_naive<<<grid, 256, 0, stream>>>(x, h, Wih, Whh, bih, bhh, out);
  }
}